// Round 2
// baseline (1008.404 us; speedup 1.0000x reference)
//
#include <hip/hip_runtime.h>
#include <hip/hip_bf16.h>

#define B_ 64
#define S_ 1024
#define LOG2E 1.4426950408889634f

typedef __attribute__((ext_vector_type(8))) short bf16x8;
typedef __attribute__((ext_vector_type(4))) float f32x4;

// ---- workspace layout (bf16 elems unless noted) ----
// xw_frag : [2][4][1024][256][16]  = 33,554,432   (64 MiB)
// bi      : [64][1024][128]        =  8,388,608   (16 MiB)
// u_frag  : [2][256][4][2][8]      =     32,768
// mask_ws : u8 [1024][64]          =     65,536 B
static constexpr size_t XW_ELEMS = 33554432ull;
static constexpr size_t BI_ELEMS = 8388608ull;
static constexpr size_t U_ELEMS  = 32768ull;

__device__ inline float bf2f(unsigned short u) {
    union { unsigned int i; float f; } v;
    v.i = ((unsigned int)u) << 16;
    return v.f;
}

// ---------------- K0: U -> per-lane B-fragment order, scaled by log2e ----------------
__global__ void k_uprep(const float* __restrict__ Uf, const float* __restrict__ Ub,
                        __hip_bfloat16* __restrict__ u_frag) {
    const int d = blockIdx.x;
    const float* U = d ? Ub : Uf;
    const int tid = threadIdx.x;
    const int w = tid >> 6, l = tid & 63;
    __hip_bfloat16* o = u_frag + (size_t)(d * 256 + tid) * 64;
#pragma unroll
    for (int n = 0; n < 4; ++n)
#pragma unroll
        for (int kc = 0; kc < 2; ++kc)
#pragma unroll
            for (int j = 0; j < 8; ++j) {
                const int k   = kc * 32 + ((l >> 4) << 3) + j;
                const int col = n * 64 + (w << 4) + (l & 15);   // gate n, h = 16w + (l&15)
                o[(n * 2 + kc) * 8 + j] = (__hip_bfloat16)(U[k * 256 + col] * LOG2E);
            }
}

// ---------------- K1: xw fragments = log2e * (embed[tok] @ W + b) ----------------
__global__ __launch_bounds__(256) void k_xw(
    const int* __restrict__ inputs, const float* __restrict__ embed_table,
    const float* __restrict__ Wf, const float* __restrict__ bf_,
    const float* __restrict__ Wb, const float* __restrict__ bb_,
    __hip_bfloat16* __restrict__ xw_frag) {
    const int dir = blockIdx.y;
    const float* W    = dir ? Wb  : Wf;
    const float* bias = dir ? bb_ : bf_;
    const int bg = blockIdx.x >> 9;          // batch group 0..3
    const int s0 = (blockIdx.x & 511) * 2;   // 2 sequence positions
    __shared__ __align__(16) float a_lds[32][128];
    const int tid = threadIdx.x;
    // rows r: b = bg*16 + (r&15), s = s0 + (r>>4)
    for (int i = tid; i < 32 * 128; i += 256) {
        const int r = i >> 7, k = i & 127;
        const int b = bg * 16 + (r & 15), s = s0 + (r >> 4);
        const int tok = inputs[b * 1024 + s];
        a_lds[r][k] = embed_table[(size_t)tok * 128 + k];
    }
    __syncthreads();
    const int g = tid;                        // output column 0..255
    float acc[32];
    const float bv = bias[g];
#pragma unroll
    for (int r = 0; r < 32; ++r) acc[r] = bv;
    for (int k4 = 0; k4 < 32; ++k4) {
        const float w0 = W[(k4 * 4 + 0) * 256 + g];
        const float w1 = W[(k4 * 4 + 1) * 256 + g];
        const float w2 = W[(k4 * 4 + 2) * 256 + g];
        const float w3 = W[(k4 * 4 + 3) * 256 + g];
#pragma unroll
        for (int r = 0; r < 32; ++r) {
            const float4 av = *reinterpret_cast<const float4*>(&a_lds[r][k4 * 4]);
            acc[r] = fmaf(av.x, w0, fmaf(av.y, w1, fmaf(av.z, w2, fmaf(av.w, w3, acc[r]))));
        }
    }
    // scatter to fragment layout
    const int w = (g >> 4) & 3, n = g >> 6, c15 = g & 15;
#pragma unroll
    for (int r = 0; r < 32; ++r) {
        const int bl = r & 15, ss = s0 + (r >> 4);
        const int tid_t = w * 64 + ((bl >> 2) << 4) + c15;
        const size_t off = (((size_t)(dir * 4 + bg) * 1024 + ss) * 256 + tid_t) * 16
                         + (n * 4 + (bl & 3));
        xw_frag[off] = (__hip_bfloat16)(acc[r] * LOG2E);
    }
}

// ---------------- K2: MFMA-batched masked LSTM recurrence ----------------
// 8 blocks: (dir, batch-group of 16). 4 waves; wave w owns cols (gate n)*16 + h in [16w,16w+16).
__global__ __launch_bounds__(256, 1) void k_rec(
    const __hip_bfloat16* __restrict__ xw_frag,
    const __hip_bfloat16* __restrict__ u_frag,
    const unsigned char* __restrict__ mask_ws,
    __hip_bfloat16* __restrict__ bi) {
    const int bid = blockIdx.x;
    const int d = bid >> 2, bg = bid & 3;
    const int tid = threadIdx.x, w = tid >> 6, l = tid & 63;

    // B fragments (loop-invariant)
    bf16x8 bfr[4][2];
    {
        const bf16x8* up = (const bf16x8*)(u_frag + (size_t)(d * 256 + tid) * 64);
#pragma unroll
        for (int n = 0; n < 4; ++n)
#pragma unroll
            for (int kc = 0; kc < 2; ++kc) bfr[n][kc] = up[n * 2 + kc];
    }

    __shared__ __align__(16) unsigned short hbuf[2][1024];   // [buf][batch*64 + swizzled]
    for (int i = tid; i < 2048; i += 256) hbuf[0][i] = 0;    // flat zero of both bufs
    __syncthreads();

    // A-frag read byte offsets (batch = l&15)
    const int arow = l & 15;
    const int sw = ((arow >> 2) & 3) << 1;
    const int aoff0 = arow * 128 + (((l >> 4)     ^ sw) & 7) * 16;
    const int aoff1 = arow * 128 + (((4 + (l >> 4)) ^ sw) & 7) * 16;
    // h write: batch = 4*(l>>4)+r, h = 16w + (l&15)
    const int wch = ((2 * w + ((l & 15) >> 3)) ^ ((l >> 4) << 1)) & 7;
    const int woffbase = (l >> 4) * 512 + wch * 16 + (l & 7) * 2;   // + r*128 bytes

    unsigned short* bi_u = (unsigned short*)bi;
    size_t bioff[4];
#pragma unroll
    for (int r = 0; r < 4; ++r)
        bioff[r] = (size_t)(bg * 16 + 4 * (l >> 4) + r) * 1024 * 128
                 + d * 64 + 16 * w + (l & 15);

    float c_st[4] = {0.f, 0.f, 0.f, 0.f};
    float h_st[4] = {0.f, 0.f, 0.f, 0.f};

    const size_t xwbase = (size_t)(d * 4 + bg) * 1024;
    const int time0 = d ? 1023 : 0;
    const uint4* xp = (const uint4*)(xw_frag + ((xwbase + time0) * 256 + tid) * 16);
    uint4 xa = xp[0], xb = xp[1];
    unsigned int m4 = *(const unsigned int*)(mask_ws + time0 * 64 + ((l >> 4) << 2));

    for (int t = 0; t < 1024; ++t) {
        const int time = d ? 1023 - t : t;
        const uint4 cxa = xa, cxb = xb;
        const unsigned int cm4 = m4;
        // prefetch t+1
        {
            const int t1 = (t + 1 < 1024) ? t + 1 : t;
            const int timen = d ? 1023 - t1 : t1;
            const uint4* np = (const uint4*)(xw_frag + ((xwbase + timen) * 256 + tid) * 16);
            xa = np[0]; xb = np[1];
            m4 = *(const unsigned int*)(mask_ws + timen * 64 + ((l >> 4) << 2));
        }
        // A fragments from current h buffer
        const char* hb = (const char*)(hbuf[0] + (t & 1) * 1024);
        const bf16x8 a0 = *(const bf16x8*)(hb + aoff0);
        const bf16x8 a1 = *(const bf16x8*)(hb + aoff1);
        // unpack xw C-init (16 bf16, slot = n*4 + r)
        float z[16];
        {
            const unsigned int du[8] = {cxa.x, cxa.y, cxa.z, cxa.w, cxb.x, cxb.y, cxb.z, cxb.w};
#pragma unroll
            for (int q = 0; q < 8; ++q) {
                z[2 * q]     = __builtin_bit_cast(float, du[q] << 16);
                z[2 * q + 1] = __builtin_bit_cast(float, du[q] & 0xffff0000u);
            }
        }
        f32x4 acc[4];
#pragma unroll
        for (int n = 0; n < 4; ++n) {
            f32x4 ci = {z[n * 4 + 0], z[n * 4 + 1], z[n * 4 + 2], z[n * 4 + 3]};
            ci = __builtin_amdgcn_mfma_f32_16x16x32_bf16(a0, bfr[n][0], ci, 0, 0, 0);
            acc[n] = __builtin_amdgcn_mfma_f32_16x16x32_bf16(a1, bfr[n][1], ci, 0, 0, 0);
        }
        unsigned short* hw = hbuf[0] + ((t + 1) & 1) * 1024;
#pragma unroll
        for (int r = 0; r < 4; ++r) {
            const float zi = acc[0][r], zf = acc[1][r], zg = acc[2][r], zo = acc[3][r];
            const float iv = __builtin_amdgcn_rcpf(1.f + __builtin_amdgcn_exp2f(-zi));
            const float fv = __builtin_amdgcn_rcpf(1.f + __builtin_amdgcn_exp2f(-zf));
            const float ov = __builtin_amdgcn_rcpf(1.f + __builtin_amdgcn_exp2f(-zo));
            const float eg = __builtin_amdgcn_exp2f(-2.f * zg);
            const float tg = (1.f - eg) * __builtin_amdgcn_rcpf(1.f + eg);
            const float cn = fv * c_st[r] + iv * tg;
            const float e2 = __builtin_amdgcn_exp2f(-2.f * LOG2E * cn);
            const float th = (1.f - e2) * __builtin_amdgcn_rcpf(1.f + e2);
            const float hn = ov * th;
            const bool m = (cm4 >> (r * 8)) & 1u;
            const float h2 = m ? hn : h_st[r];
            c_st[r] = m ? cn : c_st[r];
            h_st[r] = h2;
            const unsigned short hb16 = __builtin_bit_cast(unsigned short, (__hip_bfloat16)h2);
            hw[(woffbase + r * 128) >> 1] = hb16;
            bi_u[bioff[r] + (size_t)time * 128] = hb16;
        }
        __syncthreads();
    }
}

// ---------------- K3: event_logits ----------------
__global__ __launch_bounds__(1024) void k_logits(
    const __hip_bfloat16* __restrict__ bi, const float* __restrict__ Wt,
    const float* __restrict__ bt, float* __restrict__ out) {
    const int tid = threadIdx.x;
    const int b = tid >> 4, cls = tid & 15;
    const __hip_bfloat16* row = bi + ((size_t)b * S_ + (S_ - 1)) * 128;
    float acc = bt[cls];
    for (int k = 0; k < 128; ++k)
        acc = fmaf((float)row[k], Wt[k * 16 + cls], acc);
    out[tid] = 1.f / (1.f + __expf(-acc));
}

// ---------------- K4: expert-dedup einsum, direct scatter ----------------
__global__ __launch_bounds__(256) void k_args(
    const __hip_bfloat16* __restrict__ bi,
    const float* __restrict__ ev_table, const int* __restrict__ evt,
    const float* __restrict__ W_arg, const float* __restrict__ b_arg,
    float* __restrict__ out_args) {
    const int e = blockIdx.x;
    const int rowbase = blockIdx.y * 64;
    const int cc = rowbase >> 10;
    __shared__ float feat[64][169];
    __shared__ __align__(16) float w[1280];
    __shared__ float partial[4][64][8];
    __shared__ int   evt_l[64];
    __shared__ float bg[8];
    const int tid = threadIdx.x;
    for (int i = tid; i < 1280; i += 256) w[i] = W_arg[(size_t)e * 1280 + i];
    if (tid < 64) evt_l[tid] = evt[tid];
    if (tid < 8)  bg[tid] = b_arg[e * 8 + tid];
    const ushort2* bi2 = reinterpret_cast<const ushort2*>(bi) + (size_t)rowbase * 64;
    for (int i = tid; i < 64 * 64; i += 256) {
        const int r = i >> 6, k2 = i & 63;
        const ushort2 v = bi2[(size_t)r * 64 + k2];
        feat[r][k2 * 2]     = bf2f(v.x);
        feat[r][k2 * 2 + 1] = bf2f(v.y);
    }
    {
        const int ie = evt[cc];
        const float* evrow = ev_table + (size_t)ie * 32;
        for (int i = tid; i < 64 * 32; i += 256) {
            const int r = i >> 5, k = i & 31;
            feat[r][128 + k] = evrow[k];
        }
    }
    __syncthreads();
    const int r = tid & 63, seg = tid >> 6;
    float acc[8];
#pragma unroll
    for (int a = 0; a < 8; ++a) acc[a] = 0.f;
    const int f0 = seg * 40;
    for (int f = f0; f < f0 + 40; ++f) {
        const float fv = feat[r][f];
        const float4 w0 = *reinterpret_cast<const float4*>(&w[f * 8]);
        const float4 w1 = *reinterpret_cast<const float4*>(&w[f * 8 + 4]);
        acc[0] = fmaf(fv, w0.x, acc[0]);
        acc[1] = fmaf(fv, w0.y, acc[1]);
        acc[2] = fmaf(fv, w0.z, acc[2]);
        acc[3] = fmaf(fv, w0.w, acc[3]);
        acc[4] = fmaf(fv, w1.x, acc[4]);
        acc[5] = fmaf(fv, w1.y, acc[5]);
        acc[6] = fmaf(fv, w1.z, acc[6]);
        acc[7] = fmaf(fv, w1.w, acc[7]);
    }
#pragma unroll
    for (int a = 0; a < 8; ++a) partial[seg][r][a] = acc[a];
    __syncthreads();
    for (int o = tid; o < 512; o += 256) {
        const int rr = o >> 3, a = o & 7;
        const float v = bg[a] + partial[0][rr][a] + partial[1][rr][a]
                              + partial[2][rr][a] + partial[3][rr][a];
        const size_t base = ((size_t)(rowbase + rr)) * 8 + a;
        for (int b = 0; b < 64; ++b) {
            if (evt_l[b] == e)
                out_args[(size_t)b * (64ull * 1024 * 8) + base] = v;
        }
    }
}

// ---------------- K5: mask (float output + packed byte layout for k_rec) ----------------
__global__ __launch_bounds__(256) void k_mask(const int* __restrict__ inputs,
                                              float* __restrict__ om,
                                              unsigned char* __restrict__ mws) {
    const int i = blockIdx.x * 256 + threadIdx.x;    // b*1024 + s
    const int b = i >> 10, s = i & 1023;
    const int nz = (inputs[i] != 0) ? 1 : 0;
    om[i] = (float)nz;
    mws[s * 64 + b] = (unsigned char)nz;
}

extern "C" void kernel_launch(void* const* d_in, const int* in_sizes, int n_in,
                              void* d_out, int out_size, void* d_ws, size_t ws_size,
                              hipStream_t stream) {
    const int*   inputs = (const int*)d_in[0];
    const int*   evt    = (const int*)d_in[1];
    const float* embed  = (const float*)d_in[2];
    const float* Wf     = (const float*)d_in[3];
    const float* Uf     = (const float*)d_in[4];
    const float* bf_    = (const float*)d_in[5];
    const float* Wb     = (const float*)d_in[6];
    const float* Ub     = (const float*)d_in[7];
    const float* bb_    = (const float*)d_in[8];
    const float* evtab  = (const float*)d_in[9];
    const float* Wt     = (const float*)d_in[10];
    const float* bt     = (const float*)d_in[11];
    const float* W_arg  = (const float*)d_in[12];
    const float* b_arg  = (const float*)d_in[13];

    float* out        = (float*)d_out;
    float* out_logits = out;
    float* out_args   = out + 1024;
    float* out_mask   = out + 1024 + 33554432;

    __hip_bfloat16* xw_frag = (__hip_bfloat16*)d_ws;
    __hip_bfloat16* bi      = xw_frag + XW_ELEMS;
    __hip_bfloat16* u_frag  = bi + BI_ELEMS;
    unsigned char*  mask_ws = (unsigned char*)(u_frag + U_ELEMS);

    k_uprep <<<dim3(2),        256, 0, stream>>>(Uf, Ub, u_frag);
    k_mask  <<<dim3(256),      256, 0, stream>>>(inputs, out_mask, mask_ws);
    k_xw    <<<dim3(2048, 2),  256, 0, stream>>>(inputs, embed, Wf, bf_, Wb, bb_, xw_frag);
    k_rec   <<<dim3(8),        256, 0, stream>>>(xw_frag, u_frag, mask_ws, bi);
    k_logits<<<dim3(1),       1024, 0, stream>>>(bi, Wt, bt, out_logits);
    k_args  <<<dim3(15, 1024), 256, 0, stream>>>(bi, evtab, evt, W_arg, b_arg, out_args);
}